// Round 1
// baseline (1517.160 us; speedup 1.0000x reference)
//
#include <hip/hip_runtime.h>
#include <hip/hip_bf16.h>

typedef __bf16 bf16x8 __attribute__((ext_vector_type(8)));
typedef __bf16 bf16x4v __attribute__((ext_vector_type(4)));
typedef float f32x4 __attribute__((ext_vector_type(4)));

#define MFMA(a, b, c) __builtin_amdgcn_mfma_f32_16x16x32_bf16((a), (b), (c), 0, 0, 0)
#define NEG_BIG (-1e30f)

// ---- LDS layout: 4 wave-private regions + aliased exchange regions -------
// Per wave: q[64][36] | k[64][36] | vt[32][72]; p[64][68] aliases q+k span.
// After sync S1 the whole space is reused: otr[64][268] (o exchange), then
// wout staging [64][264] per round.
#define QK_LD 36    // 8B-aligned b64 frags; reads land on the 4-cycle floor
#define VT_LD 72    // 16B-aligned b128 frags
#define P_LD 68     // 8B-aligned b64 frags
#define OTR_LD 268  // 268*2B=536B rows: quad scatter hits distinct bank sets
#define XO_LD 264   // wout stage stride (b128-aligned frags)
#define WAVE_ELS (2304 + 2304 + 2304)    // 6912 els = 13824 B
#define TOTAL_ELS (4 * WAVE_ELS)         // 27648 els = 55296 B -> 2 blocks/CU

static __device__ inline bf16x8 ld8x2(const __bf16* p) {
  bf16x4v lo = *(const bf16x4v*)p;
  bf16x4v hi = *(const bf16x4v*)(p + 4);
  bf16x8 r;
  r[0] = lo[0]; r[1] = lo[1]; r[2] = lo[2]; r[3] = lo[3];
  r[4] = hi[0]; r[5] = hi[1]; r[6] = hi[2]; r[7] = hi[3];
  return r;
}

// ---------------------------------------------------------------- prep -----
// bias is emitted in C-fragment order: [h][mt][nt][lane][r] so the attn
// kernel initializes sim acc with one float4 load per (mt,nt).
__global__ __launch_bounds__(256) void prep_kernel(
    const float* __restrict__ w_qkv, const float* __restrict__ w_out,
    const float* __restrict__ rel_emb, const int* __restrict__ rel_idx,
    __bf16* __restrict__ wqkv_b, __bf16* __restrict__ wout_b,
    float* __restrict__ bias) {
  const float kScale = 0.17677669529663687f;  // 32^-0.5, folded into Wq
  int idx = blockIdx.x * 256 + threadIdx.x;
  if (idx < 196608) {  // w_qkv (768x256) -> bf16, q rows pre-scaled
    float v = w_qkv[idx];
    if (idx < 65536) v *= kScale;
    wqkv_b[idx] = (__bf16)v;
  } else if (idx < 262144) {  // w_out (256x256) -> bf16
    int j = idx - 196608;
    wout_b[j] = (__bf16)w_out[j];
  } else if (idx < 294912) {  // bias in fragment order, -1e30 beyond 49
    int j = idx - 262144;  // [0, 32768)
    int h = j >> 12;
    int mt = (j >> 10) & 3;
    int nt = (j >> 8) & 3;
    int lane = (j >> 2) & 63;
    int r = j & 3;
    int row = mt * 16 + ((lane >> 4) << 2) + r;  // C row = mt*16 + quad*4 + r
    int col = nt * 16 + (lane & 15);             // C col = nt*16 + l16
    float v = NEG_BIG;
    if (row < 49 && col < 49) v = rel_emb[rel_idx[row * 49 + col] * 8 + h];
    bias[j] = v;
  }
}

// ---------------------------------------------------------------- main -----
// One block per window, 4 waves. Wave w owns heads {2w, 2w+1} end-to-end
// (qkv -> sim -> softmax -> PV) with NO cross-wave barriers; weights read
// directly from L2-hot global. Only the out-projection exchanges data:
// 2 syncs for the o-transpose + 2 per wout staging round = 10 total.
// MFMA 16x16x32 bf16 layouts (HW-verified):
//   A: m=lane&15, k=quad*8+j   B: n=lane&15, k=quad*8+j
//   C/D: col=lane&15, row=quad*4+reg
__global__ __launch_bounds__(256, 2) void attn_kernel(
    const float* __restrict__ x, const __bf16* __restrict__ wqkv,
    const __bf16* __restrict__ wout, const float* __restrict__ bias,
    float* __restrict__ out) {
  __shared__ __attribute__((aligned(16))) __bf16 sm[TOTAL_ELS];

  const int tid = threadIdx.x;
  const int wave = tid >> 6;
  const int lane = tid & 63;
  const int quad = lane >> 4;
  const int l16 = lane & 15;
  const int i0 = wave * 16 + quad * 4;  // out-proj C/D row base
  const int am = wave * 16 + l16;       // out-proj A operand row

  const f32x4 fzero = {0.f, 0.f, 0.f, 0.f};
  const float* xg = x + (size_t)blockIdx.x * 12544;

  __bf16* mq = sm + wave * WAVE_ELS;  // q [64][36]
  __bf16* mk = mq + 2304;             // k [64][36]
  __bf16* mv = mk + 2304;             // vT [32][72]
  __bf16* mp = mq;                    // p [64][68] aliases q+k (4352 <= 4608)

  f32x4 oacc[2][4][2];  // per-head PV output, held until the o exchange

#pragma unroll
  for (int hh = 0; hh < 2; ++hh) {
    const int h = wave * 2 + hh;

    // ---- qkv: C(64x96) = x(64x256) @ Wh^T, B-frags straight from global.
    // Waves touch disjoint wqkv rows -> block reads wqkv exactly once.
    f32x4 acc[4][6];
#pragma unroll
    for (int mt = 0; mt < 4; ++mt)
#pragma unroll
      for (int nt = 0; nt < 6; ++nt) acc[mt][nt] = fzero;

#pragma unroll
    for (int k2 = 0; k2 < 8; ++k2) {
      bf16x8 b[6];
#pragma unroll
      for (int nt = 0; nt < 6; ++nt) {
        int grow = (nt >> 1) * 256 + h * 32 + (nt & 1) * 16 + l16;
        b[nt] = *(const bf16x8*)&wqkv[grow * 256 + k2 * 32 + quad * 8];
      }
#pragma unroll
      for (int mt = 0; mt < 4; ++mt) {
        int xr = mt * 16 + l16;
        if (xr > 48) xr = 48;  // clamp: rows 49..63 get finite garbage, masked later
        const float* xp = xg + xr * 256 + k2 * 32 + quad * 8;
        float4 v0 = *(const float4*)xp;
        float4 v1 = *(const float4*)(xp + 4);
        bf16x8 a;
        a[0] = (__bf16)v0.x; a[1] = (__bf16)v0.y; a[2] = (__bf16)v0.z; a[3] = (__bf16)v0.w;
        a[4] = (__bf16)v1.x; a[5] = (__bf16)v1.y; a[6] = (__bf16)v1.z; a[7] = (__bf16)v1.w;
#pragma unroll
        for (int nt = 0; nt < 6; ++nt) acc[mt][nt] = MFMA(a, b[nt], acc[mt][nt]);
      }
    }

    // ---- scatter q,k row-major and v transposed into wave-private LDS
    // (no barrier: same wave writes and reads; compiler inserts lgkmcnt)
#pragma unroll
    for (int mt = 0; mt < 4; ++mt) {
      int row = mt * 16 + quad * 4;
#pragma unroll
      for (int t = 0; t < 2; ++t) {
#pragma unroll
        for (int r = 0; r < 4; ++r) {
          mq[(row + r) * QK_LD + t * 16 + l16] = (__bf16)acc[mt][t][r];
          mk[(row + r) * QK_LD + t * 16 + l16] = (__bf16)acc[mt][2 + t][r];
        }
        bf16x4v pv;
#pragma unroll
        for (int r = 0; r < 4; ++r) pv[r] = (__bf16)acc[mt][4 + t][r];
        *(bf16x4v*)&mv[(t * 16 + l16) * VT_LD + row] = pv;
      }
    }

    // ---- sim = q.k^T + bias; acc initialized from fragment-ordered bias
    f32x4 sim[4][4];
    const float* bb = bias + (h << 12) + (lane << 2);
#pragma unroll
    for (int mt = 0; mt < 4; ++mt)
#pragma unroll
      for (int nt = 0; nt < 4; ++nt)
        sim[mt][nt] = *(const f32x4*)&bb[(mt * 4 + nt) << 8];

    bf16x8 aq[4];
#pragma unroll
    for (int mt = 0; mt < 4; ++mt)
      aq[mt] = ld8x2(&mq[(mt * 16 + l16) * QK_LD + quad * 8]);
#pragma unroll
    for (int nt = 0; nt < 4; ++nt) {
      bf16x8 bk = ld8x2(&mk[(nt * 16 + l16) * QK_LD + quad * 8]);
#pragma unroll
      for (int mt = 0; mt < 4; ++mt) sim[mt][nt] = MFMA(aq[mt], bk, sim[mt][nt]);
    }

    // ---- row softmax: row lives in one 16-lane quad -> shfl_xor 1,2,4,8
#pragma unroll
    for (int mt = 0; mt < 4; ++mt) {
#pragma unroll
      for (int r = 0; r < 4; ++r) {
        float mx = fmaxf(fmaxf(sim[mt][0][r], sim[mt][1][r]),
                         fmaxf(sim[mt][2][r], sim[mt][3][r]));
        mx = fmaxf(mx, __shfl_xor(mx, 1));
        mx = fmaxf(mx, __shfl_xor(mx, 2));
        mx = fmaxf(mx, __shfl_xor(mx, 4));
        mx = fmaxf(mx, __shfl_xor(mx, 8));
        float e0 = __expf(sim[mt][0][r] - mx), e1 = __expf(sim[mt][1][r] - mx);
        float e2 = __expf(sim[mt][2][r] - mx), e3 = __expf(sim[mt][3][r] - mx);
        float sum = e0 + e1 + e2 + e3;
        sum += __shfl_xor(sum, 1);
        sum += __shfl_xor(sum, 2);
        sum += __shfl_xor(sum, 4);
        sum += __shfl_xor(sum, 8);
        float rs = 1.0f / sum;
        int row = mt * 16 + quad * 4 + r;
        mp[row * P_LD + l16] = (__bf16)(e0 * rs);
        mp[row * P_LD + 16 + l16] = (__bf16)(e1 * rs);
        mp[row * P_LD + 32 + l16] = (__bf16)(e2 * rs);
        mp[row * P_LD + 48 + l16] = (__bf16)(e3 * rs);
      }
    }

    // ---- o_h = P(64x64) @ V(64x32), all within the wave
#pragma unroll
    for (int mt = 0; mt < 4; ++mt)
#pragma unroll
      for (int t = 0; t < 2; ++t) oacc[hh][mt][t] = fzero;
#pragma unroll
    for (int kk = 0; kk < 2; ++kk) {
      bf16x8 bv[2];
#pragma unroll
      for (int t = 0; t < 2; ++t)
        bv[t] = *(const bf16x8*)&mv[(t * 16 + l16) * VT_LD + kk * 32 + quad * 8];
#pragma unroll
      for (int mt = 0; mt < 4; ++mt) {
        bf16x8 ap = ld8x2(&mp[(mt * 16 + l16) * P_LD + kk * 32 + quad * 8]);
#pragma unroll
        for (int t = 0; t < 2; ++t) oacc[hh][mt][t] = MFMA(ap, bv[t], oacc[hh][mt][t]);
      }
    }
  }

  // ---- o exchange: otr[64][268] aliases the per-wave regions (S1 ensures
  // every wave is done reading its own q/k/p/vt before any overwrite)
  __syncthreads();  // S1
#pragma unroll
  for (int hh = 0; hh < 2; ++hh) {
    int cb = (wave * 2 + hh) * 32;
#pragma unroll
    for (int mt = 0; mt < 4; ++mt)
#pragma unroll
      for (int t = 0; t < 2; ++t)
#pragma unroll
        for (int r = 0; r < 4; ++r)
          sm[(mt * 16 + quad * 4 + r) * OTR_LD + cb + t * 16 + l16] =
              (__bf16)oacc[hh][mt][t][r];
  }
  __syncthreads();  // S2: otr visible
  bf16x8 ofr[8];
#pragma unroll
  for (int k8 = 0; k8 < 8; ++k8)
    ofr[k8] = ld8x2(&sm[am * OTR_LD + k8 * 32 + quad * 8]);

  // ---- out projection: out(64x256) = o @ w_out^T; stage 64 wout rows/round
  for (int rr = 0; rr < 4; ++rr) {
    __syncthreads();  // rr=0: ofr gathers done; rr>0: prev B-frag reads done
    for (int i = tid; i < 2048; i += 256) {
      int lr = i >> 5, c = (i & 31) * 8;
      *(bf16x8*)&sm[lr * XO_LD + c] = *(const bf16x8*)&wout[(rr * 64 + lr) * 256 + c];
    }
    __syncthreads();
#pragma unroll
    for (int e2 = 0; e2 < 2; ++e2) {
      f32x4 fa[2];
      fa[0] = fzero;
      fa[1] = fzero;
#pragma unroll
      for (int kk = 0; kk < 8; ++kk) {
#pragma unroll
        for (int t = 0; t < 2; ++t) {
          bf16x8 bw = *(const bf16x8*)&sm[(e2 * 32 + t * 16 + l16) * XO_LD + kk * 32 + quad * 8];
          fa[t] = MFMA(ofr[kk], bw, fa[t]);
        }
      }
      float* ob = out + (size_t)blockIdx.x * 12544 + (rr * 2 + e2) * 32;
#pragma unroll
      for (int t = 0; t < 2; ++t)
#pragma unroll
        for (int r = 0; r < 4; ++r) {
          int row = i0 + r;
          if (row < 49) ob[row * 256 + t * 16 + l16] = fa[t][r];
        }
    }
  }
}

// ---------------------------------------------------------------- launch ---
extern "C" void kernel_launch(void* const* d_in, const int* in_sizes, int n_in,
                              void* d_out, int out_size, void* d_ws, size_t ws_size,
                              hipStream_t stream) {
  (void)in_sizes; (void)n_in; (void)out_size; (void)ws_size;
  const float* x = (const float*)d_in[0];
  const float* w_qkv = (const float*)d_in[1];
  const float* w_out = (const float*)d_in[2];
  const float* rel_emb = (const float*)d_in[3];
  const int* rel_idx = (const int*)d_in[4];
  float* out = (float*)d_out;

  char* ws = (char*)d_ws;
  __bf16* wqkv_b = (__bf16*)ws;             // 768*256*2 = 393216 B
  __bf16* wout_b = (__bf16*)(ws + 393216);  // 256*256*2 = 131072 B
  float* bias = (float*)(ws + 524288);      // 8*4*4*64*4*4 = 131072 B

  prep_kernel<<<1152, 256, 0, stream>>>(w_qkv, w_out, rel_emb, rel_idx,
                                        wqkv_b, wout_b, bias);
  attn_kernel<<<4096, 256, 0, stream>>>(x, wqkv_b, wout_b, bias, out);
}

// Round 3
// 894.530 us; speedup vs baseline: 1.6960x; 1.6960x over previous
//
#include <hip/hip_runtime.h>
#include <hip/hip_bf16.h>

typedef __bf16 bf16x8 __attribute__((ext_vector_type(8)));
typedef __bf16 bf16x4v __attribute__((ext_vector_type(4)));
typedef float f32x4 __attribute__((ext_vector_type(4)));

#define MFMA(a, b, c) __builtin_amdgcn_mfma_f32_16x16x32_bf16((a), (b), (c), 0, 0, 0)
#define NEG_BIG (-1e30f)

// ---- LDS layout ----------------------------------------------------------
// Prologue: x staged as [64][XO_LD] bf16 (33792 B). After A-fragments are
// preloaded to regs, the same space is reused for the per-head transpose
// buffers q/k/vt/p/otr (13568 els = 27136 B). Total 33792 B -> 4 blocks/CU.
#define XO_LD 264   // x stage stride (b128-aligned frags)
#define QK_LD 36    // q,k [64][36]  (2xb64 frags)
#define VT_LD 72    // vT [32][72]  (b128-aligned frags)
#define P_LD 68     // p [64][68]   (2xb64 frags)
#define OTR_LD 36   // o transpose buf [64][36] (2xb64 frags)
#define Q_OFF 0
#define K_OFF 2304
#define VT_OFF 4608
#define P_OFF 6912
#define OTR_OFF 11264
#define TOTAL_ELS (64 * XO_LD)  // 16896 els = 33792 B

static __device__ inline bf16x8 ld8x2(const __bf16* p) {
  bf16x4v lo = *(const bf16x4v*)p;
  bf16x4v hi = *(const bf16x4v*)(p + 4);
  bf16x8 r;
  r[0] = lo[0]; r[1] = lo[1]; r[2] = lo[2]; r[3] = lo[3];
  r[4] = hi[0]; r[5] = hi[1]; r[6] = hi[2]; r[7] = hi[3];
  return r;
}

// ---------------------------------------------------------------- prep -----
// Packs weights into exact MFMA B-fragment order so the attn kernel reads
// them as fully-coalesced 16B/lane streams with zero LDS staging:
//   wqkv_f[((h*6+nt)*8+k2)*64 + lane][0..8) = wqkv[grow][k2*32+quad*8+j]
//     grow = (nt>>1)*256 + h*32 + (nt&1)*16 + l16  (q rows pre-scaled)
//   wout_f[((ntile*8+kk)*64 + lane][0..8) = wout[ntile*16+l16][kk*32+quad*8+j]
// bias in C-fragment order [h][mt][nt][lane][r], -1e30 outside 49x49.
__global__ __launch_bounds__(256) void prep_kernel(
    const float* __restrict__ w_qkv, const float* __restrict__ w_out,
    const float* __restrict__ rel_emb, const int* __restrict__ rel_idx,
    __bf16* __restrict__ wqkv_f, __bf16* __restrict__ wout_f,
    float* __restrict__ bias) {
  const float kScale = 0.17677669529663687f;  // 32^-0.5, folded into Wq
  int idx = blockIdx.x * 256 + threadIdx.x;
  if (idx < 24576) {  // wqkv pack: 8h * 6nt * 8k2 * 64 lanes
    int lane = idx & 63, k2 = (idx >> 6) & 7;
    int hn = idx >> 9;
    int nt = hn % 6, h = hn / 6;
    int quad = lane >> 4, l16 = lane & 15;
    int grow = (nt >> 1) * 256 + h * 32 + (nt & 1) * 16 + l16;
    const float* src = w_qkv + grow * 256 + k2 * 32 + quad * 8;
    float s = (nt < 2) ? kScale : 1.0f;
    bf16x8 d;
#pragma unroll
    for (int j = 0; j < 8; ++j) d[j] = (__bf16)(src[j] * s);
    *(bf16x8*)&wqkv_f[idx * 8] = d;
  } else if (idx < 32768) {  // wout pack: 16 ntile * 8kk * 64 lanes
    int j2 = idx - 24576;
    int lane = j2 & 63, kk = (j2 >> 6) & 7, ntile = j2 >> 9;
    int quad = lane >> 4, l16 = lane & 15;
    const float* src = w_out + (ntile * 16 + l16) * 256 + kk * 32 + quad * 8;
    bf16x8 d;
#pragma unroll
    for (int j = 0; j < 8; ++j) d[j] = (__bf16)src[j];
    *(bf16x8*)&wout_f[j2 * 8] = d;
  } else if (idx < 65536) {  // bias in fragment order
    int j = idx - 32768;  // [0, 32768)
    int h = j >> 12;
    int mt = (j >> 10) & 3;
    int nt = (j >> 8) & 3;
    int lane = (j >> 2) & 63;
    int r = j & 3;
    int row = mt * 16 + ((lane >> 4) << 2) + r;  // C row = mt*16 + quad*4 + r
    int col = nt * 16 + (lane & 15);             // C col = nt*16 + l16
    float v = NEG_BIG;
    if (row < 49 && col < 49) v = rel_emb[rel_idx[row * 49 + col] * 8 + h];
    bias[j] = v;
  }
}

// ---------------------------------------------------------------- main -----
// One block per window, 4 waves cooperating per head; wave w owns M rows
// [16w,16w+16). Weights come from fragment-packed global (L2-hot) -> no
// staging, no staging barriers. Barriers: 2 prologue + 3/head = 26 total.
// MFMA 16x16x32 bf16 layouts (HW-verified):
//   A: m=lane&15, k=quad*8+j   B: n=lane&15, k=quad*8+j
//   C/D: col=lane&15, row=quad*4+reg
__global__ __launch_bounds__(256, 4) void attn_kernel(
    const float* __restrict__ x, const __bf16* __restrict__ wqkv,
    const __bf16* __restrict__ wout, const float* __restrict__ bias,
    float* __restrict__ out) {
  __shared__ __attribute__((aligned(16))) __bf16 sm[TOTAL_ELS];

  const int tid = threadIdx.x;
  const int wave = tid >> 6;
  const int lane = tid & 63;
  const int quad = lane >> 4;
  const int l16 = lane & 15;
  const int i0 = wave * 16 + quad * 4;  // C/D row base
  const int am = wave * 16 + l16;       // A/B operand row

  const f32x4 fzero = {0.f, 0.f, 0.f, 0.f};

  // ---- stage x window (49x256 fp32 -> bf16), zero-pad rows 49..63
  {
    const float4* xg = (const float4*)(x + (size_t)blockIdx.x * 12544);
    for (int i = tid; i < 3136; i += 256) {
      float4 v = xg[i];
      int row = i >> 6, c4 = (i & 63) << 2;
      bf16x4v t;
      t[0] = (__bf16)v.x; t[1] = (__bf16)v.y; t[2] = (__bf16)v.z; t[3] = (__bf16)v.w;
      *(bf16x4v*)&sm[row * XO_LD + c4] = t;
    }
    bf16x4v z;
    z[0] = z[1] = z[2] = z[3] = (__bf16)0.0f;
    for (int i = tid; i < 960; i += 256) {
      int row = 49 + (i >> 6), c4 = (i & 63) << 2;
      *(bf16x4v*)&sm[row * XO_LD + c4] = z;
    }
  }
  __syncthreads();

  // ---- preload x A-fragments (K=256 -> 8 frags), reused for all 8 heads
  bf16x8 afr[8];
#pragma unroll
  for (int kk = 0; kk < 8; ++kk)
    afr[kk] = *(const bf16x8*)&sm[am * XO_LD + kk * 32 + quad * 8];
  __syncthreads();  // x region is now dead; q/k/vt/p/otr alias it

  bf16x8 ofr[8];  // per-head out-proj A-fragments

  // ---- per-head fused attention
  for (int h = 0; h < 8; ++h) {
    // qkv GEMM: C(64x96) = x(64x256) @ W^T, B-frags straight from packed
    // global (each wave streams 48 x 1KB coalesced loads, L2/L1-hot)
    f32x4 acc[6];
#pragma unroll
    for (int t = 0; t < 6; ++t) acc[t] = fzero;
    {
      const __bf16* wb = wqkv + (size_t)h * 24576;  // 6nt*8k2*512
#pragma unroll
      for (int k2 = 0; k2 < 8; ++k2) {
        bf16x8 a = afr[k2];
#pragma unroll
        for (int nt = 0; nt < 6; ++nt) {
          bf16x8 b = *(const bf16x8*)&wb[(nt * 8 + k2) * 512 + lane * 8];
          acc[nt] = MFMA(a, b, acc[nt]);
        }
      }
    }

    // bias prefetch into regs (fragment order: one float4 per nt)
    f32x4 sim[4];
    {
      const float* bb = bias + (h << 12) + (wave << 10) + (lane << 2);
#pragma unroll
      for (int nt = 0; nt < 4; ++nt) sim[nt] = *(const f32x4*)&bb[nt << 8];
    }

    // scatter q,k row-major and v transposed into LDS
#pragma unroll
    for (int t = 0; t < 2; ++t) {
#pragma unroll
      for (int r = 0; r < 4; ++r) {
        sm[Q_OFF + (i0 + r) * QK_LD + t * 16 + l16] = (__bf16)acc[t][r];
        sm[K_OFF + (i0 + r) * QK_LD + t * 16 + l16] = (__bf16)acc[2 + t][r];
      }
      bf16x4v pv;
#pragma unroll
      for (int r = 0; r < 4; ++r) pv[r] = (__bf16)acc[4 + t][r];
      *(bf16x4v*)&sm[VT_OFF + (t * 16 + l16) * VT_LD + i0] = pv;
    }
    __syncthreads();  // D1: q/k/vt visible

    // sim = q.k^T + bias (K=32 -> 1 MFMA per N-tile)
    {
      bf16x8 a = ld8x2(&sm[Q_OFF + am * QK_LD + quad * 8]);
#pragma unroll
      for (int nt = 0; nt < 4; ++nt) {
        bf16x8 b = ld8x2(&sm[K_OFF + (nt * 16 + l16) * QK_LD + quad * 8]);
        sim[nt] = MFMA(a, b, sim[nt]);
      }
    }

    // row softmax: row lives in one 16-lane quad -> shfl_xor 1,2,4,8
#pragma unroll
    for (int r = 0; r < 4; ++r) {
      float mx = fmaxf(fmaxf(sim[0][r], sim[1][r]), fmaxf(sim[2][r], sim[3][r]));
      mx = fmaxf(mx, __shfl_xor(mx, 1));
      mx = fmaxf(mx, __shfl_xor(mx, 2));
      mx = fmaxf(mx, __shfl_xor(mx, 4));
      mx = fmaxf(mx, __shfl_xor(mx, 8));
      float e0 = __expf(sim[0][r] - mx), e1 = __expf(sim[1][r] - mx);
      float e2 = __expf(sim[2][r] - mx), e3 = __expf(sim[3][r] - mx);
      float sum = e0 + e1 + e2 + e3;
      sum += __shfl_xor(sum, 1);
      sum += __shfl_xor(sum, 2);
      sum += __shfl_xor(sum, 4);
      sum += __shfl_xor(sum, 8);
      float rs = 1.0f / sum;
      int row = i0 + r;
      sm[P_OFF + row * P_LD + l16] = (__bf16)(e0 * rs);
      sm[P_OFF + row * P_LD + 16 + l16] = (__bf16)(e1 * rs);
      sm[P_OFF + row * P_LD + 32 + l16] = (__bf16)(e2 * rs);
      sm[P_OFF + row * P_LD + 48 + l16] = (__bf16)(e3 * rs);
    }
    __syncthreads();  // D2: p visible

    // o_h = P(64x64) @ V(64x32)
    f32x4 oa[2];
    oa[0] = fzero;
    oa[1] = fzero;
#pragma unroll
    for (int kk = 0; kk < 2; ++kk) {
      bf16x8 a = ld8x2(&sm[P_OFF + am * P_LD + kk * 32 + quad * 8]);
#pragma unroll
      for (int t = 0; t < 2; ++t) {
        bf16x8 b = *(const bf16x8*)&sm[VT_OFF + (t * 16 + l16) * VT_LD + kk * 32 + quad * 8];
        oa[t] = MFMA(a, b, oa[t]);
      }
    }
    // C-layout -> A-layout round trip for the out-proj fragment
#pragma unroll
    for (int t = 0; t < 2; ++t)
#pragma unroll
      for (int r = 0; r < 4; ++r)
        sm[OTR_OFF + (i0 + r) * OTR_LD + t * 16 + l16] = (__bf16)oa[t][r];
    __syncthreads();  // D3: otr visible; also fences q/k/vt/p reuse next head
    ofr[h] = ld8x2(&sm[OTR_OFF + am * OTR_LD + quad * 8]);
  }

  // ---- out projection: out(64x256) = o @ w_out^T, B-frags from packed
  // global — no LDS, no barriers.
  float* ob_base = out + (size_t)blockIdx.x * 12544;
  for (int ct = 0; ct < 8; ++ct) {  // 32-col chunks
    f32x4 fa[2];
    fa[0] = fzero;
    fa[1] = fzero;
#pragma unroll
    for (int kk = 0; kk < 8; ++kk) {
#pragma unroll
      for (int t = 0; t < 2; ++t) {
        bf16x8 bw = *(const bf16x8*)&wout[((ct * 2 + t) * 8 + kk) * 512 + lane * 8];
        fa[t] = MFMA(ofr[kk], bw, fa[t]);
      }
    }
    float* ob = ob_base + ct * 32;
#pragma unroll
    for (int t = 0; t < 2; ++t)
#pragma unroll
      for (int r = 0; r < 4; ++r) {
        int row = i0 + r;
        if (row < 49) ob[row * 256 + t * 16 + l16] = fa[t][r];
      }
  }
}

// ---------------------------------------------------------------- launch ---
extern "C" void kernel_launch(void* const* d_in, const int* in_sizes, int n_in,
                              void* d_out, int out_size, void* d_ws, size_t ws_size,
                              hipStream_t stream) {
  (void)in_sizes; (void)n_in; (void)out_size; (void)ws_size;
  const float* x = (const float*)d_in[0];
  const float* w_qkv = (const float*)d_in[1];
  const float* w_out = (const float*)d_in[2];
  const float* rel_emb = (const float*)d_in[3];
  const int* rel_idx = (const int*)d_in[4];
  float* out = (float*)d_out;

  char* ws = (char*)d_ws;
  __bf16* wqkv_f = (__bf16*)ws;             // 768*256*2 = 393216 B
  __bf16* wout_f = (__bf16*)(ws + 393216);  // 256*256*2 = 131072 B
  float* bias = (float*)(ws + 524288);      // 8*4*4*64*4*4 = 131072 B

  prep_kernel<<<256, 256, 0, stream>>>(w_qkv, w_out, rel_emb, rel_idx,
                                       wqkv_f, wout_f, bias);
  attn_kernel<<<4096, 256, 0, stream>>>(x, wqkv_f, wout_f, bias, out);
}

// Round 4
// 872.069 us; speedup vs baseline: 1.7397x; 1.0258x over previous
//
#include <hip/hip_runtime.h>
#include <hip/hip_bf16.h>

typedef __bf16 bf16x8 __attribute__((ext_vector_type(8)));
typedef __bf16 bf16x4v __attribute__((ext_vector_type(4)));
typedef float f32x4 __attribute__((ext_vector_type(4)));

#define MFMA(a, b, c) __builtin_amdgcn_mfma_f32_16x16x32_bf16((a), (b), (c), 0, 0, 0)
#define NEG_BIG (-1e30f)

// ---- LDS layout ----------------------------------------------------------
// Only k and vt are read cross-wave; q and p are wave-private (A-fragments,
// own rows), and the o-transpose buffer aliases the dead p region. No x
// stage (A-frags load directly from global). 11264 els = 22528 B ->
// 7 blocks/CU (LDS-limited), 28 waves/CU.
#define QK_LD 36  // q,k [64][36]  (2xb64 frags)
#define VT_LD 72  // vT [32][72]  (b128-aligned frags)
#define P_LD 68   // p [64][68]   (2xb64 frags); otr reuses this region
#define K_OFF 0
#define VT_OFF 2304
#define Q_OFF 4608
#define P_OFF 6912
#define TOTAL_ELS 11264  // 22528 B

static __device__ inline bf16x8 ld8x2(const __bf16* p) {
  bf16x4v lo = *(const bf16x4v*)p;
  bf16x4v hi = *(const bf16x4v*)(p + 4);
  bf16x8 r;
  r[0] = lo[0]; r[1] = lo[1]; r[2] = lo[2]; r[3] = lo[3];
  r[4] = hi[0]; r[5] = hi[1]; r[6] = hi[2]; r[7] = hi[3];
  return r;
}

// ---------------------------------------------------------------- prep -----
// Packs weights into exact MFMA B-fragment order so the attn kernel reads
// them as fully-coalesced 16B/lane streams with zero LDS staging:
//   wqkv_f[((h*6+nt)*8+k2)*64 + lane][0..8) = wqkv[grow][k2*32+quad*8+j]
//     grow = (nt>>1)*256 + h*32 + (nt&1)*16 + l16  (q rows pre-scaled)
//   wout_f[((ntile*8+kk)*64 + lane][0..8) = wout[ntile*16+l16][kk*32+quad*8+j]
// bias in C-fragment order [h][mt][nt][lane][r], -1e30 outside 49x49.
__global__ __launch_bounds__(256) void prep_kernel(
    const float* __restrict__ w_qkv, const float* __restrict__ w_out,
    const float* __restrict__ rel_emb, const int* __restrict__ rel_idx,
    __bf16* __restrict__ wqkv_f, __bf16* __restrict__ wout_f,
    float* __restrict__ bias) {
  const float kScale = 0.17677669529663687f;  // 32^-0.5, folded into Wq
  int idx = blockIdx.x * 256 + threadIdx.x;
  if (idx < 24576) {  // wqkv pack: 8h * 6nt * 8k2 * 64 lanes
    int lane = idx & 63, k2 = (idx >> 6) & 7;
    int hn = idx >> 9;
    int nt = hn % 6, h = hn / 6;
    int quad = lane >> 4, l16 = lane & 15;
    int grow = (nt >> 1) * 256 + h * 32 + (nt & 1) * 16 + l16;
    const float* src = w_qkv + grow * 256 + k2 * 32 + quad * 8;
    float s = (nt < 2) ? kScale : 1.0f;
    bf16x8 d;
#pragma unroll
    for (int j = 0; j < 8; ++j) d[j] = (__bf16)(src[j] * s);
    *(bf16x8*)&wqkv_f[idx * 8] = d;
  } else if (idx < 32768) {  // wout pack: 16 ntile * 8kk * 64 lanes
    int j2 = idx - 24576;
    int lane = j2 & 63, kk = (j2 >> 6) & 7, ntile = j2 >> 9;
    int quad = lane >> 4, l16 = lane & 15;
    const float* src = w_out + (ntile * 16 + l16) * 256 + kk * 32 + quad * 8;
    bf16x8 d;
#pragma unroll
    for (int j = 0; j < 8; ++j) d[j] = (__bf16)src[j];
    *(bf16x8*)&wout_f[j2 * 8] = d;
  } else if (idx < 65536) {  // bias in fragment order
    int j = idx - 32768;  // [0, 32768)
    int h = j >> 12;
    int mt = (j >> 10) & 3;
    int nt = (j >> 8) & 3;
    int lane = (j >> 2) & 63;
    int r = j & 3;
    int row = mt * 16 + ((lane >> 4) << 2) + r;  // C row = mt*16 + quad*4 + r
    int col = nt * 16 + (lane & 15);             // C col = nt*16 + l16
    float v = NEG_BIG;
    if (row < 49 && col < 49) v = rel_emb[rel_idx[row * 49 + col] * 8 + h];
    bias[j] = v;
  }
}

// ---------------------------------------------------------------- main -----
// One block per window, 4 waves cooperating per head; wave w owns M rows
// [16w,16w+16). Weights from fragment-packed global (L2-hot). Barriers:
// 2/head (15 total) — q/p/otr are wave-private so only k/vt need fencing.
// The top-of-head barrier sits AFTER head h+1's qkv loads+MFMAs, letting
// weight-load latency overlap other waves' head-h softmax/PV.
// MFMA 16x16x32 bf16 layouts (HW-verified):
//   A: m=lane&15, k=quad*8+j   B: n=lane&15, k=quad*8+j
//   C/D: col=lane&15, row=quad*4+reg
__global__ __launch_bounds__(256, 7) void attn_kernel(
    const float* __restrict__ x, const __bf16* __restrict__ wqkv,
    const __bf16* __restrict__ wout, const float* __restrict__ bias,
    float* __restrict__ out) {
  __shared__ __attribute__((aligned(16))) __bf16 sm[TOTAL_ELS];

  const int tid = threadIdx.x;
  const int wave = tid >> 6;
  const int lane = tid & 63;
  const int quad = lane >> 4;
  const int l16 = lane & 15;
  const int i0 = wave * 16 + quad * 4;  // C/D row base
  const int am = wave * 16 + l16;       // A/B operand row

  const f32x4 fzero = {0.f, 0.f, 0.f, 0.f};

  // ---- A-fragments straight from global x (fp32 -> bf16 in regs).
  // Rows 49..63 clamp to row 48: finite garbage, masked by bias / store.
  bf16x8 afr[8];
  {
    const float* xrow =
        x + (size_t)blockIdx.x * 12544 + (am > 48 ? 48 : am) * 256;
#pragma unroll
    for (int k2 = 0; k2 < 8; ++k2) {
      const float* xp = xrow + k2 * 32 + quad * 8;
      float4 v0 = *(const float4*)xp;
      float4 v1 = *(const float4*)(xp + 4);
      bf16x8 a;
      a[0] = (__bf16)v0.x; a[1] = (__bf16)v0.y; a[2] = (__bf16)v0.z; a[3] = (__bf16)v0.w;
      a[4] = (__bf16)v1.x; a[5] = (__bf16)v1.y; a[6] = (__bf16)v1.z; a[7] = (__bf16)v1.w;
      afr[k2] = a;
    }
  }

  bf16x8 ofr[8];  // per-head out-proj A-fragments

  // ---- per-head fused attention
  for (int h = 0; h < 8; ++h) {
    // qkv GEMM: C(64x96) = x(64x256) @ W^T, B-frags from packed global.
    // No shared-LDS access here -> overlaps other waves' prev-head tail.
    f32x4 acc[6];
#pragma unroll
    for (int t = 0; t < 6; ++t) acc[t] = fzero;
    {
      const __bf16* wb = wqkv + (size_t)h * 24576;  // 6nt*8k2*512
#pragma unroll
      for (int k2 = 0; k2 < 8; ++k2) {
        bf16x8 a = afr[k2];
#pragma unroll
        for (int nt = 0; nt < 6; ++nt) {
          bf16x8 b = *(const bf16x8*)&wb[(nt * 8 + k2) * 512 + lane * 8];
          acc[nt] = MFMA(a, b, acc[nt]);
        }
      }
    }

    // bias prefetch (fragment order: one float4 per nt)
    f32x4 sim[4];
    {
      const float* bb = bias + (h << 12) + (wave << 10) + (lane << 2);
#pragma unroll
      for (int nt = 0; nt < 4; ++nt) sim[nt] = *(const f32x4*)&bb[nt << 8];
    }

    if (h) __syncthreads();  // prev head's k/vt fully consumed by all waves

    // scatter q,k row-major and v transposed into LDS
#pragma unroll
    for (int t = 0; t < 2; ++t) {
#pragma unroll
      for (int r = 0; r < 4; ++r) {
        sm[Q_OFF + (i0 + r) * QK_LD + t * 16 + l16] = (__bf16)acc[t][r];
        sm[K_OFF + (i0 + r) * QK_LD + t * 16 + l16] = (__bf16)acc[2 + t][r];
      }
      bf16x4v pv;
#pragma unroll
      for (int r = 0; r < 4; ++r) pv[r] = (__bf16)acc[4 + t][r];
      *(bf16x4v*)&sm[VT_OFF + (t * 16 + l16) * VT_LD + i0] = pv;
    }
    __syncthreads();  // k/vt visible to all waves

    // sim = q.k^T + bias (K=32 -> 1 MFMA per N-tile)
    {
      bf16x8 a = ld8x2(&sm[Q_OFF + am * QK_LD + quad * 8]);
#pragma unroll
      for (int nt = 0; nt < 4; ++nt) {
        bf16x8 b = ld8x2(&sm[K_OFF + (nt * 16 + l16) * QK_LD + quad * 8]);
        sim[nt] = MFMA(a, b, sim[nt]);
      }
    }

    // row softmax WITHOUT max-subtraction: sim ~ N(0,1)-scale (weights are
    // dim^-0.5-scaled), so exp can't overflow; masked cols are -1e30 -> 0.
    // Rows >=49 have sum==0 -> rs forced to 0 (keeps p NaN-free).
#pragma unroll
    for (int r = 0; r < 4; ++r) {
      float e0 = __expf(sim[0][r]), e1 = __expf(sim[1][r]);
      float e2 = __expf(sim[2][r]), e3 = __expf(sim[3][r]);
      float sum = e0 + e1 + e2 + e3;
      sum += __shfl_xor(sum, 1);
      sum += __shfl_xor(sum, 2);
      sum += __shfl_xor(sum, 4);
      sum += __shfl_xor(sum, 8);
      float rs = (sum > 0.f) ? (1.0f / sum) : 0.f;
      int row = i0 + r;
      sm[P_OFF + row * P_LD + l16] = (__bf16)(e0 * rs);
      sm[P_OFF + row * P_LD + 16 + l16] = (__bf16)(e1 * rs);
      sm[P_OFF + row * P_LD + 32 + l16] = (__bf16)(e2 * rs);
      sm[P_OFF + row * P_LD + 48 + l16] = (__bf16)(e3 * rs);
    }
    // p is wave-private: write->read ordered by the in-wave LDS pipe.

    // o_h = P(64x64) @ V(64x32)
    f32x4 oa[2];
    oa[0] = fzero;
    oa[1] = fzero;
#pragma unroll
    for (int kk = 0; kk < 2; ++kk) {
      bf16x8 a = ld8x2(&sm[P_OFF + am * P_LD + kk * 32 + quad * 8]);
#pragma unroll
      for (int t = 0; t < 2; ++t) {
        bf16x8 b = *(const bf16x8*)&sm[VT_OFF + (t * 16 + l16) * VT_LD + kk * 32 + quad * 8];
        oa[t] = MFMA(a, b, oa[t]);
      }
    }
    // C->A round trip for the out-proj fragment, reusing the dead p region
    // (wave-private; p cols [0,32) are dead after the PV reads above)
#pragma unroll
    for (int t = 0; t < 2; ++t)
#pragma unroll
      for (int r = 0; r < 4; ++r)
        sm[P_OFF + (i0 + r) * P_LD + t * 16 + l16] = (__bf16)oa[t][r];
    ofr[h] = ld8x2(&sm[P_OFF + am * P_LD + quad * 8]);
  }

  // ---- out projection: out(64x256) = o @ w_out^T, B-frags from packed
  // global — no LDS, no barriers.
  float* ob_base = out + (size_t)blockIdx.x * 12544;
  for (int ct = 0; ct < 8; ++ct) {  // 32-col chunks
    f32x4 fa[2];
    fa[0] = fzero;
    fa[1] = fzero;
#pragma unroll
    for (int kk = 0; kk < 8; ++kk) {
#pragma unroll
      for (int t = 0; t < 2; ++t) {
        bf16x8 bw = *(const bf16x8*)&wout[((ct * 2 + t) * 8 + kk) * 512 + lane * 8];
        fa[t] = MFMA(ofr[kk], bw, fa[t]);
      }
    }
    float* ob = ob_base + ct * 32;
#pragma unroll
    for (int t = 0; t < 2; ++t)
#pragma unroll
      for (int r = 0; r < 4; ++r) {
        int row = i0 + r;
        if (row < 49) ob[row * 256 + t * 16 + l16] = fa[t][r];
      }
  }
}

// ---------------------------------------------------------------- launch ---
extern "C" void kernel_launch(void* const* d_in, const int* in_sizes, int n_in,
                              void* d_out, int out_size, void* d_ws, size_t ws_size,
                              hipStream_t stream) {
  (void)in_sizes; (void)n_in; (void)out_size; (void)ws_size;
  const float* x = (const float*)d_in[0];
  const float* w_qkv = (const float*)d_in[1];
  const float* w_out = (const float*)d_in[2];
  const float* rel_emb = (const float*)d_in[3];
  const int* rel_idx = (const int*)d_in[4];
  float* out = (float*)d_out;

  char* ws = (char*)d_ws;
  __bf16* wqkv_f = (__bf16*)ws;             // 768*256*2 = 393216 B
  __bf16* wout_f = (__bf16*)(ws + 393216);  // 256*256*2 = 131072 B
  float* bias = (float*)(ws + 524288);      // 8*4*4*64*4*4 = 131072 B

  prep_kernel<<<256, 256, 0, stream>>>(w_qkv, w_out, rel_emb, rel_idx,
                                       wqkv_f, wout_f, bias);
  attn_kernel<<<4096, 256, 0, stream>>>(x, wqkv_f, wout_f, bias, out);
}

// Round 5
// 762.250 us; speedup vs baseline: 1.9904x; 1.1441x over previous
//
#include <hip/hip_runtime.h>
#include <hip/hip_bf16.h>

typedef __bf16 bf16x8 __attribute__((ext_vector_type(8)));
typedef __bf16 bf16x4v __attribute__((ext_vector_type(4)));
typedef float f32x4 __attribute__((ext_vector_type(4)));

#define MFMA(a, b, c) __builtin_amdgcn_mfma_f32_16x16x32_bf16((a), (b), (c), 0, 0, 0)
#define NEG_BIG (-1e30f)

// ---- LDS layout ----------------------------------------------------------
// Only k and vt are read cross-wave; q and p are wave-private (A-fragments,
// own rows), and the o-transpose buffer aliases the dead p region. No x
// stage (A-frags load directly from global). 11264 els = 22528 B.
#define QK_LD 36  // q,k [64][36]  (2xb64 frags)
#define VT_LD 72  // vT [32][72]  (b128-aligned frags)
#define P_LD 68   // p [64][68]   (2xb64 frags); otr reuses this region
#define K_OFF 0
#define VT_OFF 2304
#define Q_OFF 4608
#define P_OFF 6912
#define TOTAL_ELS 11264  // 22528 B

static __device__ inline bf16x8 ld8x2(const __bf16* p) {
  bf16x4v lo = *(const bf16x4v*)p;
  bf16x4v hi = *(const bf16x4v*)(p + 4);
  bf16x8 r;
  r[0] = lo[0]; r[1] = lo[1]; r[2] = lo[2]; r[3] = lo[3];
  r[4] = hi[0]; r[5] = hi[1]; r[6] = hi[2]; r[7] = hi[3];
  return r;
}

// ---------------------------------------------------------------- prep -----
// Packs weights into exact MFMA B-fragment order so the attn kernel reads
// them as fully-coalesced 16B/lane streams with zero LDS staging:
//   wqkv_f[((h*6+nt)*8+k2)*64 + lane][0..8) = wqkv[grow][k2*32+quad*8+j]
//     grow = (nt>>1)*256 + h*32 + (nt&1)*16 + l16  (q rows pre-scaled)
//   wout_f[((ntile*8+kk)*64 + lane][0..8) = wout[ntile*16+l16][kk*32+quad*8+j]
// bias in C-fragment order [h][mt][nt][lane][r], -1e30 outside 49x49.
__global__ __launch_bounds__(256) void prep_kernel(
    const float* __restrict__ w_qkv, const float* __restrict__ w_out,
    const float* __restrict__ rel_emb, const int* __restrict__ rel_idx,
    __bf16* __restrict__ wqkv_f, __bf16* __restrict__ wout_f,
    float* __restrict__ bias) {
  const float kScale = 0.17677669529663687f;  // 32^-0.5, folded into Wq
  int idx = blockIdx.x * 256 + threadIdx.x;
  if (idx < 24576) {  // wqkv pack: 8h * 6nt * 8k2 * 64 lanes
    int lane = idx & 63, k2 = (idx >> 6) & 7;
    int hn = idx >> 9;
    int nt = hn % 6, h = hn / 6;
    int quad = lane >> 4, l16 = lane & 15;
    int grow = (nt >> 1) * 256 + h * 32 + (nt & 1) * 16 + l16;
    const float* src = w_qkv + grow * 256 + k2 * 32 + quad * 8;
    float s = (nt < 2) ? kScale : 1.0f;
    bf16x8 d;
#pragma unroll
    for (int j = 0; j < 8; ++j) d[j] = (__bf16)(src[j] * s);
    *(bf16x8*)&wqkv_f[idx * 8] = d;
  } else if (idx < 32768) {  // wout pack: 16 ntile * 8kk * 64 lanes
    int j2 = idx - 24576;
    int lane = j2 & 63, kk = (j2 >> 6) & 7, ntile = j2 >> 9;
    int quad = lane >> 4, l16 = lane & 15;
    const float* src = w_out + (ntile * 16 + l16) * 256 + kk * 32 + quad * 8;
    bf16x8 d;
#pragma unroll
    for (int j = 0; j < 8; ++j) d[j] = (__bf16)src[j];
    *(bf16x8*)&wout_f[j2 * 8] = d;
  } else if (idx < 65536) {  // bias in fragment order
    int j = idx - 32768;  // [0, 32768)
    int h = j >> 12;
    int mt = (j >> 10) & 3;
    int nt = (j >> 8) & 3;
    int lane = (j >> 2) & 63;
    int r = j & 3;
    int row = mt * 16 + ((lane >> 4) << 2) + r;  // C row = mt*16 + quad*4 + r
    int col = nt * 16 + (lane & 15);             // C col = nt*16 + l16
    float v = NEG_BIG;
    if (row < 49 && col < 49) v = rel_emb[rel_idx[row * 49 + col] * 8 + h];
    bias[j] = v;
  }
}

// ---------------------------------------------------------------- main -----
// One block per window, 4 waves cooperating per head; wave w owns M rows
// [16w,16w+16). Weights from fragment-packed global (L2-hot). Barriers:
// 2/head — q/p/otr are wave-private so only k/vt need fencing. The
// top-of-head barrier sits AFTER head h+1's qkv loads+MFMAs, letting
// weight-load latency overlap other waves' head-h softmax/PV.
// Head loop is FULLY UNROLLED so ofr[h]/afr[k2] are static-indexed ->
// registers (rule: runtime-indexed ext_vector arrays go to scratch).
// __launch_bounds__(256,6): ~85-VGPR budget, no spills; LDS (22.5 KB) is
// then the occupancy limiter.
// MFMA 16x16x32 bf16 layouts (HW-verified):
//   A: m=lane&15, k=quad*8+j   B: n=lane&15, k=quad*8+j
//   C/D: col=lane&15, row=quad*4+reg
__global__ __launch_bounds__(256, 6) void attn_kernel(
    const float* __restrict__ x, const __bf16* __restrict__ wqkv,
    const __bf16* __restrict__ wout, const float* __restrict__ bias,
    float* __restrict__ out) {
  __shared__ __attribute__((aligned(16))) __bf16 sm[TOTAL_ELS];

  const int tid = threadIdx.x;
  const int wave = tid >> 6;
  const int lane = tid & 63;
  const int quad = lane >> 4;
  const int l16 = lane & 15;
  const int i0 = wave * 16 + quad * 4;  // C/D row base
  const int am = wave * 16 + l16;       // A/B operand row

  const f32x4 fzero = {0.f, 0.f, 0.f, 0.f};

  // ---- A-fragments straight from global x (fp32 -> bf16 in regs).
  // Rows 49..63 clamp to row 48: finite garbage, masked by bias / store.
  bf16x8 afr[8];
  {
    const float* xrow =
        x + (size_t)blockIdx.x * 12544 + (am > 48 ? 48 : am) * 256;
#pragma unroll
    for (int k2 = 0; k2 < 8; ++k2) {
      const float* xp = xrow + k2 * 32 + quad * 8;
      float4 v0 = *(const float4*)xp;
      float4 v1 = *(const float4*)(xp + 4);
      bf16x8 a;
      a[0] = (__bf16)v0.x; a[1] = (__bf16)v0.y; a[2] = (__bf16)v0.z; a[3] = (__bf16)v0.w;
      a[4] = (__bf16)v1.x; a[5] = (__bf16)v1.y; a[6] = (__bf16)v1.z; a[7] = (__bf16)v1.w;
      afr[k2] = a;
    }
  }

  bf16x8 ofr[8];  // per-head out-proj A-fragments (static-indexed)

  // ---- per-head fused attention (fully unrolled: static ofr/afr indexing)
#pragma unroll
  for (int h = 0; h < 8; ++h) {
    // qkv GEMM: C(64x96) = x(64x256) @ W^T, B-frags from packed global.
    // No shared-LDS access here -> overlaps other waves' prev-head tail.
    f32x4 acc[6];
#pragma unroll
    for (int t = 0; t < 6; ++t) acc[t] = fzero;
    {
      const __bf16* wb = wqkv + (size_t)h * 24576;  // 6nt*8k2*512
#pragma unroll
      for (int k2 = 0; k2 < 8; ++k2) {
        bf16x8 a = afr[k2];
#pragma unroll
        for (int nt = 0; nt < 6; ++nt) {
          bf16x8 b = *(const bf16x8*)&wb[(nt * 8 + k2) * 512 + lane * 8];
          acc[nt] = MFMA(a, b, acc[nt]);
        }
      }
    }

    if (h) __syncthreads();  // prev head's k/vt fully consumed by all waves

    // scatter q,k row-major and v transposed into LDS
#pragma unroll
    for (int t = 0; t < 2; ++t) {
#pragma unroll
      for (int r = 0; r < 4; ++r) {
        sm[Q_OFF + (i0 + r) * QK_LD + t * 16 + l16] = (__bf16)acc[t][r];
        sm[K_OFF + (i0 + r) * QK_LD + t * 16 + l16] = (__bf16)acc[2 + t][r];
      }
      bf16x4v pv;
#pragma unroll
      for (int r = 0; r < 4; ++r) pv[r] = (__bf16)acc[4 + t][r];
      *(bf16x4v*)&sm[VT_OFF + (t * 16 + l16) * VT_LD + i0] = pv;
    }

    // bias prefetch (fragment order: one float4 per nt); placed after the
    // scatter so acc is dead -> lower peak VGPR; latency hides under bar2.
    f32x4 sim[4];
    {
      const float* bb = bias + (h << 12) + (wave << 10) + (lane << 2);
#pragma unroll
      for (int nt = 0; nt < 4; ++nt) sim[nt] = *(const f32x4*)&bb[nt << 8];
    }
    __syncthreads();  // k/vt visible to all waves

    // sim = q.k^T + bias (K=32 -> 1 MFMA per N-tile)
    {
      bf16x8 a = ld8x2(&sm[Q_OFF + am * QK_LD + quad * 8]);
#pragma unroll
      for (int nt = 0; nt < 4; ++nt) {
        bf16x8 b = ld8x2(&sm[K_OFF + (nt * 16 + l16) * QK_LD + quad * 8]);
        sim[nt] = MFMA(a, b, sim[nt]);
      }
    }

    // row softmax WITHOUT max-subtraction: sim ~ N(0,1)-scale (weights are
    // dim^-0.5-scaled), so exp can't overflow; masked cols are -1e30 -> 0.
    // Rows >=49 have sum==0 -> rs forced to 0 (keeps p NaN-free).
#pragma unroll
    for (int r = 0; r < 4; ++r) {
      float e0 = __expf(sim[0][r]), e1 = __expf(sim[1][r]);
      float e2 = __expf(sim[2][r]), e3 = __expf(sim[3][r]);
      float sum = e0 + e1 + e2 + e3;
      sum += __shfl_xor(sum, 1);
      sum += __shfl_xor(sum, 2);
      sum += __shfl_xor(sum, 4);
      sum += __shfl_xor(sum, 8);
      float rs = (sum > 0.f) ? (1.0f / sum) : 0.f;
      int row = i0 + r;
      sm[P_OFF + row * P_LD + l16] = (__bf16)(e0 * rs);
      sm[P_OFF + row * P_LD + 16 + l16] = (__bf16)(e1 * rs);
      sm[P_OFF + row * P_LD + 32 + l16] = (__bf16)(e2 * rs);
      sm[P_OFF + row * P_LD + 48 + l16] = (__bf16)(e3 * rs);
    }
    // p is wave-private: write->read ordered by the in-wave LDS pipe.

    // o_h = P(64x64) @ V(64x32)
    f32x4 oa[2];
    oa[0] = fzero;
    oa[1] = fzero;
#pragma unroll
    for (int kk = 0; kk < 2; ++kk) {
      bf16x8 a = ld8x2(&sm[P_OFF + am * P_LD + kk * 32 + quad * 8]);
#pragma unroll
      for (int t = 0; t < 2; ++t) {
        bf16x8 b = *(const bf16x8*)&sm[VT_OFF + (t * 16 + l16) * VT_LD + kk * 32 + quad * 8];
        oa[t] = MFMA(a, b, oa[t]);
      }
    }
    // C->A round trip for the out-proj fragment, reusing the dead p region
    // (wave-private; p cols [0,32) are dead after the PV reads above)
#pragma unroll
    for (int t = 0; t < 2; ++t)
#pragma unroll
      for (int r = 0; r < 4; ++r)
        sm[P_OFF + (i0 + r) * P_LD + t * 16 + l16] = (__bf16)oa[t][r];
    ofr[h] = ld8x2(&sm[P_OFF + am * P_LD + quad * 8]);
  }

  // ---- out projection: out(64x256) = o @ w_out^T, B-frags from packed
  // global — no LDS, no barriers.
  float* ob_base = out + (size_t)blockIdx.x * 12544;
  for (int ct = 0; ct < 8; ++ct) {  // 32-col chunks
    f32x4 fa[2];
    fa[0] = fzero;
    fa[1] = fzero;
#pragma unroll
    for (int kk = 0; kk < 8; ++kk) {
#pragma unroll
      for (int t = 0; t < 2; ++t) {
        bf16x8 bw = *(const bf16x8*)&wout[((ct * 2 + t) * 8 + kk) * 512 + lane * 8];
        fa[t] = MFMA(ofr[kk], bw, fa[t]);
      }
    }
    float* ob = ob_base + ct * 32;
#pragma unroll
    for (int t = 0; t < 2; ++t)
#pragma unroll
      for (int r = 0; r < 4; ++r) {
        int row = i0 + r;
        if (row < 49) ob[row * 256 + t * 16 + l16] = fa[t][r];
      }
  }
}

// ---------------------------------------------------------------- launch ---
extern "C" void kernel_launch(void* const* d_in, const int* in_sizes, int n_in,
                              void* d_out, int out_size, void* d_ws, size_t ws_size,
                              hipStream_t stream) {
  (void)in_sizes; (void)n_in; (void)out_size; (void)ws_size;
  const float* x = (const float*)d_in[0];
  const float* w_qkv = (const float*)d_in[1];
  const float* w_out = (const float*)d_in[2];
  const float* rel_emb = (const float*)d_in[3];
  const int* rel_idx = (const int*)d_in[4];
  float* out = (float*)d_out;

  char* ws = (char*)d_ws;
  __bf16* wqkv_f = (__bf16*)ws;             // 768*256*2 = 393216 B
  __bf16* wout_f = (__bf16*)(ws + 393216);  // 256*256*2 = 131072 B
  float* bias = (float*)(ws + 524288);      // 8*4*4*64*4*4 = 131072 B

  prep_kernel<<<256, 256, 0, stream>>>(w_qkv, w_out, rel_emb, rel_idx,
                                       wqkv_f, wout_f, bias);
  attn_kernel<<<4096, 256, 0, stream>>>(x, wqkv_f, wout_f, bias, out);
}

// Round 7
// 750.162 us; speedup vs baseline: 2.0224x; 1.0161x over previous
//
#include <hip/hip_runtime.h>
#include <hip/hip_bf16.h>

typedef __bf16 bf16x8 __attribute__((ext_vector_type(8)));
typedef __bf16 bf16x4v __attribute__((ext_vector_type(4)));
typedef float f32x4 __attribute__((ext_vector_type(4)));

#define MFMA(a, b, c) __builtin_amdgcn_mfma_f32_16x16x32_bf16((a), (b), (c), 0, 0, 0)
#define NEG_BIG (-1e30f)

// ---- LDS layout ----------------------------------------------------------
// Only k and vt are read cross-wave; q and p are wave-private (A-fragments,
// own rows), and the o-transpose buffer aliases the dead p region. No x
// stage (A-frags load directly from global). 11264 els = 22528 B.
#define QK_LD 36  // q,k [64][36]  (2xb64 frags)
#define VT_LD 72  // vT [32][72]  (b128-aligned frags)
#define P_LD 68   // p [64][68]   (2xb64 frags); otr reuses this region
#define K_OFF 0
#define VT_OFF 2304
#define Q_OFF 4608
#define P_OFF 6912
#define TOTAL_ELS 11264  // 22528 B

static __device__ inline bf16x8 ld8x2(const __bf16* p) {
  bf16x4v lo = *(const bf16x4v*)p;
  bf16x4v hi = *(const bf16x4v*)(p + 4);
  bf16x8 r;
  r[0] = lo[0]; r[1] = lo[1]; r[2] = lo[2]; r[3] = lo[3];
  r[4] = hi[0]; r[5] = hi[1]; r[6] = hi[2]; r[7] = hi[3];
  return r;
}

// ---------------------------------------------------------------- prep -----
// Packs weights into exact MFMA B-fragment order so the attn kernel reads
// them as fully-coalesced 16B/lane streams with zero LDS staging:
//   wqkv_f[((h*6+nt)*8+k2)*64 + lane][0..8) = wqkv[grow][k2*32+quad*8+j]
//     grow = (nt>>1)*256 + h*32 + (nt&1)*16 + l16  (q rows pre-scaled)
//   wout_f[((ntile*8+kk)*64 + lane][0..8) = wout[ntile*16+l16][kk*32+quad*8+j]
// bias in C-fragment order [h][mt][nt][lane][r], -1e30 outside 49x49.
__global__ __launch_bounds__(256) void prep_kernel(
    const float* __restrict__ w_qkv, const float* __restrict__ w_out,
    const float* __restrict__ rel_emb, const int* __restrict__ rel_idx,
    __bf16* __restrict__ wqkv_f, __bf16* __restrict__ wout_f,
    float* __restrict__ bias) {
  const float kScale = 0.17677669529663687f;  // 32^-0.5, folded into Wq
  int idx = blockIdx.x * 256 + threadIdx.x;
  if (idx < 24576) {  // wqkv pack: 8h * 6nt * 8k2 * 64 lanes
    int lane = idx & 63, k2 = (idx >> 6) & 7;
    int hn = idx >> 9;
    int nt = hn % 6, h = hn / 6;
    int quad = lane >> 4, l16 = lane & 15;
    int grow = (nt >> 1) * 256 + h * 32 + (nt & 1) * 16 + l16;
    const float* src = w_qkv + grow * 256 + k2 * 32 + quad * 8;
    float s = (nt < 2) ? kScale : 1.0f;
    bf16x8 d;
#pragma unroll
    for (int j = 0; j < 8; ++j) d[j] = (__bf16)(src[j] * s);
    *(bf16x8*)&wqkv_f[idx * 8] = d;
  } else if (idx < 32768) {  // wout pack: 16 ntile * 8kk * 64 lanes
    int j2 = idx - 24576;
    int lane = j2 & 63, kk = (j2 >> 6) & 7, ntile = j2 >> 9;
    int quad = lane >> 4, l16 = lane & 15;
    const float* src = w_out + (ntile * 16 + l16) * 256 + kk * 32 + quad * 8;
    bf16x8 d;
#pragma unroll
    for (int j = 0; j < 8; ++j) d[j] = (__bf16)src[j];
    *(bf16x8*)&wout_f[j2 * 8] = d;
  } else if (idx < 65536) {  // bias in fragment order
    int j = idx - 32768;  // [0, 32768)
    int h = j >> 12;
    int mt = (j >> 10) & 3;
    int nt = (j >> 8) & 3;
    int lane = (j >> 2) & 63;
    int r = j & 3;
    int row = mt * 16 + ((lane >> 4) << 2) + r;  // C row = mt*16 + quad*4 + r
    int col = nt * 16 + (lane & 15);             // C col = nt*16 + l16
    float v = NEG_BIG;
    if (row < 49 && col < 49) v = rel_emb[rel_idx[row * 49 + col] * 8 + h];
    bias[j] = v;
  }
}

// ---------------------------------------------------------------- main -----
// One block per window, 4 waves cooperating per head; wave w owns M rows
// [16w,16w+16). Weights from fragment-packed global (L2-hot). Barriers:
// 2/head — q/p/otr are wave-private so only k/vt need fencing. The
// top-of-head barrier sits AFTER head h+1's qkv loads+MFMAs, letting
// weight-load latency overlap other waves' head-h softmax/PV.
// Register budget: afr(32) + ofr(32) + acc(24) + sim(16) + temps ~= 110
// peak -> __launch_bounds__(256,4) gives a 128-VGPR budget so NOTHING is
// demoted to scratch (bounds 6/7 demoted afr+ofr -> ~500 MB of HBM spill
// traffic, rounds 4-5). 4 blocks/CU, LDS well under the 4-block limit.
// MFMA 16x16x32 bf16 layouts (HW-verified):
//   A: m=lane&15, k=quad*8+j   B: n=lane&15, k=quad*8+j
//   C/D: col=lane&15, row=quad*4+reg
__global__ __launch_bounds__(256, 4) void attn_kernel(
    const float* __restrict__ x, const __bf16* __restrict__ wqkv,
    const __bf16* __restrict__ wout, const float* __restrict__ bias,
    float* __restrict__ out) {
  __shared__ __attribute__((aligned(16))) __bf16 sm[TOTAL_ELS];

  const int tid = threadIdx.x;
  const int wave = tid >> 6;
  const int lane = tid & 63;
  const int quad = lane >> 4;
  const int l16 = lane & 15;
  const int i0 = wave * 16 + quad * 4;  // C/D row base
  const int am = wave * 16 + l16;       // A/B operand row

  const f32x4 fzero = {0.f, 0.f, 0.f, 0.f};

  // ---- A-fragments straight from global x (fp32 -> bf16 in regs).
  // Rows 49..63 clamp to row 48: finite garbage, masked by bias / store.
  bf16x8 afr[8];
  {
    const float* xrow =
        x + (size_t)blockIdx.x * 12544 + (am > 48 ? 48 : am) * 256;
#pragma unroll
    for (int k2 = 0; k2 < 8; ++k2) {
      const float* xp = xrow + k2 * 32 + quad * 8;
      float4 v0 = *(const float4*)xp;
      float4 v1 = *(const float4*)(xp + 4);
      bf16x8 a;
      a[0] = (__bf16)v0.x; a[1] = (__bf16)v0.y; a[2] = (__bf16)v0.z; a[3] = (__bf16)v0.w;
      a[4] = (__bf16)v1.x; a[5] = (__bf16)v1.y; a[6] = (__bf16)v1.z; a[7] = (__bf16)v1.w;
      afr[k2] = a;
    }
  }

  bf16x8 ofr[8];  // per-head out-proj A-fragments (static-indexed)

  // ---- per-head fused attention (fully unrolled: static ofr/afr indexing)
#pragma unroll
  for (int h = 0; h < 8; ++h) {
    // qkv GEMM: C(64x96) = x(64x256) @ W^T, B-frags from packed global.
    // No shared-LDS access here -> overlaps other waves' prev-head tail.
    f32x4 acc[6];
#pragma unroll
    for (int t = 0; t < 6; ++t) acc[t] = fzero;
    {
      const __bf16* wb = wqkv + (size_t)h * 24576;  // 6nt*8k2*512
#pragma unroll
      for (int k2 = 0; k2 < 8; ++k2) {
        bf16x8 a = afr[k2];
#pragma unroll
        for (int nt = 0; nt < 6; ++nt) {
          bf16x8 b = *(const bf16x8*)&wb[(nt * 8 + k2) * 512 + lane * 8];
          acc[nt] = MFMA(a, b, acc[nt]);
        }
      }
    }

    if (h) __syncthreads();  // prev head's k/vt fully consumed by all waves

    // scatter q,k row-major and v transposed into LDS
#pragma unroll
    for (int t = 0; t < 2; ++t) {
#pragma unroll
      for (int r = 0; r < 4; ++r) {
        sm[Q_OFF + (i0 + r) * QK_LD + t * 16 + l16] = (__bf16)acc[t][r];
        sm[K_OFF + (i0 + r) * QK_LD + t * 16 + l16] = (__bf16)acc[2 + t][r];
      }
      bf16x4v pv;
#pragma unroll
      for (int r = 0; r < 4; ++r) pv[r] = (__bf16)acc[4 + t][r];
      *(bf16x4v*)&sm[VT_OFF + (t * 16 + l16) * VT_LD + i0] = pv;
    }

    // bias prefetch (fragment order: one float4 per nt); placed after the
    // scatter so acc is dead -> lower peak VGPR; latency hides under bar2.
    f32x4 sim[4];
    {
      const float* bb = bias + (h << 12) + (wave << 10) + (lane << 2);
#pragma unroll
      for (int nt = 0; nt < 4; ++nt) sim[nt] = *(const f32x4*)&bb[nt << 8];
    }
    __syncthreads();  // k/vt visible to all waves

    // sim = q.k^T + bias (K=32 -> 1 MFMA per N-tile)
    {
      bf16x8 a = ld8x2(&sm[Q_OFF + am * QK_LD + quad * 8]);
#pragma unroll
      for (int nt = 0; nt < 4; ++nt) {
        bf16x8 b = ld8x2(&sm[K_OFF + (nt * 16 + l16) * QK_LD + quad * 8]);
        sim[nt] = MFMA(a, b, sim[nt]);
      }
    }

    // row softmax WITHOUT max-subtraction: sim ~ N(0,1)-scale (weights are
    // dim^-0.5-scaled), so exp can't overflow; masked cols are -1e30 -> 0.
    // Rows >=49 have sum==0 -> rs forced to 0 (keeps p NaN-free).
#pragma unroll
    for (int r = 0; r < 4; ++r) {
      float e0 = __expf(sim[0][r]), e1 = __expf(sim[1][r]);
      float e2 = __expf(sim[2][r]), e3 = __expf(sim[3][r]);
      float sum = e0 + e1 + e2 + e3;
      sum += __shfl_xor(sum, 1);
      sum += __shfl_xor(sum, 2);
      sum += __shfl_xor(sum, 4);
      sum += __shfl_xor(sum, 8);
      float rs = (sum > 0.f) ? (1.0f / sum) : 0.f;
      int row = i0 + r;
      sm[P_OFF + row * P_LD + l16] = (__bf16)(e0 * rs);
      sm[P_OFF + row * P_LD + 16 + l16] = (__bf16)(e1 * rs);
      sm[P_OFF + row * P_LD + 32 + l16] = (__bf16)(e2 * rs);
      sm[P_OFF + row * P_LD + 48 + l16] = (__bf16)(e3 * rs);
    }
    // p is wave-private: write->read ordered by the in-wave LDS pipe.

    // o_h = P(64x64) @ V(64x32)
    f32x4 oa[2];
    oa[0] = fzero;
    oa[1] = fzero;
#pragma unroll
    for (int kk = 0; kk < 2; ++kk) {
      bf16x8 a = ld8x2(&sm[P_OFF + am * P_LD + kk * 32 + quad * 8]);
#pragma unroll
      for (int t = 0; t < 2; ++t) {
        bf16x8 b = *(const bf16x8*)&sm[VT_OFF + (t * 16 + l16) * VT_LD + kk * 32 + quad * 8];
        oa[t] = MFMA(a, b, oa[t]);
      }
    }
    // C->A round trip for the out-proj fragment, reusing the dead p region
    // (wave-private; p cols [0,32) are dead after the PV reads above)
#pragma unroll
    for (int t = 0; t < 2; ++t)
#pragma unroll
      for (int r = 0; r < 4; ++r)
        sm[P_OFF + (i0 + r) * P_LD + t * 16 + l16] = (__bf16)oa[t][r];
    ofr[h] = ld8x2(&sm[P_OFF + am * P_LD + quad * 8]);
  }

  // ---- out projection: out(64x256) = o @ w_out^T, B-frags from packed
  // global — no LDS, no barriers.
  float* ob_base = out + (size_t)blockIdx.x * 12544;
  for (int ct = 0; ct < 8; ++ct) {  // 32-col chunks
    f32x4 fa[2];
    fa[0] = fzero;
    fa[1] = fzero;
#pragma unroll
    for (int kk = 0; kk < 8; ++kk) {
#pragma unroll
      for (int t = 0; t < 2; ++t) {
        bf16x8 bw = *(const bf16x8*)&wout[((ct * 2 + t) * 8 + kk) * 512 + lane * 8];
        fa[t] = MFMA(ofr[kk], bw, fa[t]);
      }
    }
    float* ob = ob_base + ct * 32;
#pragma unroll
    for (int t = 0; t < 2; ++t)
#pragma unroll
      for (int r = 0; r < 4; ++r) {
        int row = i0 + r;
        if (row < 49) ob[row * 256 + t * 16 + l16] = fa[t][r];
      }
  }
}

// ---------------------------------------------------------------- launch ---
extern "C" void kernel_launch(void* const* d_in, const int* in_sizes, int n_in,
                              void* d_out, int out_size, void* d_ws, size_t ws_size,
                              hipStream_t stream) {
  (void)in_sizes; (void)n_in; (void)out_size; (void)ws_size;
  const float* x = (const float*)d_in[0];
  const float* w_qkv = (const float*)d_in[1];
  const float* w_out = (const float*)d_in[2];
  const float* rel_emb = (const float*)d_in[3];
  const int* rel_idx = (const int*)d_in[4];
  float* out = (float*)d_out;

  char* ws = (char*)d_ws;
  __bf16* wqkv_f = (__bf16*)ws;             // 768*256*2 = 393216 B
  __bf16* wout_f = (__bf16*)(ws + 393216);  // 256*256*2 = 131072 B
  float* bias = (float*)(ws + 524288);      // 8*4*4*64*4*4 = 131072 B

  prep_kernel<<<256, 256, 0, stream>>>(w_qkv, w_out, rel_emb, rel_idx,
                                       wqkv_f, wout_f, bias);
  attn_kernel<<<4096, 256, 0, stream>>>(x, wqkv_f, wout_f, bias, out);
}